// Round 1
// baseline (1097.175 us; speedup 1.0000x reference)
//
#include <hip/hip_runtime.h>
#include <math.h>

#define N_NODES 50000
#define N_EDGES 800000
#define D_FEAT 128
#define HIDDEN 256

// ---------- degree ----------
__global__ void deg_kernel(const int* __restrict__ dst, float* __restrict__ deg) {
    int e = blockIdx.x * blockDim.x + threadIdx.x;
    if (e < N_EDGES) unsafeAtomicAdd(&deg[dst[e]], 1.0f);
}

// ---------- scatter x[src] -> agg1[dst], 128 floats per edge ----------
// one wave (64 lanes) per edge; each lane handles a float2 (features 2f, 2f+1)
__global__ void scatter_x(const float* __restrict__ x, const int* __restrict__ src,
                          const int* __restrict__ dst, float* __restrict__ agg) {
    int idx = blockIdx.x * blockDim.x + threadIdx.x;   // 51.2M total < 2^31
    int e = idx >> 6;
    int f = idx & 63;
    if (e < N_EDGES) {
        int s = src[e], d = dst[e];
        float2 v = *(const float2*)(x + (size_t)s * D_FEAT + 2 * f);
        float* ap = agg + (size_t)d * D_FEAT + 2 * f;
        unsafeAtomicAdd(ap + 0, v.x);
        unsafeAtomicAdd(ap + 1, v.y);
    }
}

// ---------- fused layer-1 GEMM: h = relu(mean@W1l + x@W1r + b1) ----------
// block = 256 threads, 16 rows per block, each thread owns one output column.
__global__ __launch_bounds__(256) void gemm1(
    const float* __restrict__ x, const float* __restrict__ agg,
    const float* __restrict__ deg,
    const float* __restrict__ W1l, const float* __restrict__ W1r,
    const float* __restrict__ b1, float* __restrict__ h) {
    __shared__ float xs[16 * 128];
    __shared__ float ms[16 * 128];
    __shared__ float invd[16];

    int r0 = blockIdx.x * 16;
    int tid = threadIdx.x;
    if (tid < 16) {
        invd[tid] = 1.0f / fmaxf(deg[r0 + tid], 1.0f);
    }
    __syncthreads();
    for (int i = tid; i < 16 * 128; i += 256) {
        int r = i >> 7;
        xs[i] = x[(size_t)(r0 + (i >> 7)) * 128 + (i & 127)];
        ms[i] = agg[(size_t)(r0 + (i >> 7)) * 128 + (i & 127)] * invd[r];
    }
    __syncthreads();

    float acc[16];
#pragma unroll
    for (int r = 0; r < 16; r++) acc[r] = 0.0f;

    int c = tid;  // output column 0..255
    for (int k = 0; k < 128; k++) {
        float wl = W1l[k * 256 + c];
        float wr = W1r[k * 256 + c];
#pragma unroll
        for (int r = 0; r < 16; r++) {
            acc[r] += ms[r * 128 + k] * wl + xs[r * 128 + k] * wr;
        }
    }
    float b = b1[c];
#pragma unroll
    for (int r = 0; r < 16; r++) {
        float v = acc[r] + b;
        h[(size_t)(r0 + r) * 256 + c] = v > 0.0f ? v : 0.0f;
    }
}

// ---------- p = h@W2l, s = h@W2r + b2 (one wave per row) ----------
__global__ void ps_kernel(const float* __restrict__ h, const float* __restrict__ W2l,
                          const float* __restrict__ W2r, const float* __restrict__ b2,
                          float* __restrict__ p, float* __restrict__ s) {
    int row = blockIdx.x * 4 + (threadIdx.x >> 6);
    int lane = threadIdx.x & 63;
    if (row >= N_NODES) return;
    float p0 = 0, p1 = 0, s0 = 0, s1 = 0;
#pragma unroll
    for (int j = 0; j < 4; j++) {
        int cc = lane + j * 64;
        float hv = h[(size_t)row * 256 + cc];
        p0 += hv * W2l[cc * 2 + 0];
        p1 += hv * W2l[cc * 2 + 1];
        s0 += hv * W2r[cc * 2 + 0];
        s1 += hv * W2r[cc * 2 + 1];
    }
#pragma unroll
    for (int off = 32; off > 0; off >>= 1) {
        p0 += __shfl_down(p0, off);
        p1 += __shfl_down(p1, off);
        s0 += __shfl_down(s0, off);
        s1 += __shfl_down(s1, off);
    }
    if (lane == 0) {
        p[row * 2 + 0] = p0;
        p[row * 2 + 1] = p1;
        s[row * 2 + 0] = s0 + b2[0];
        s[row * 2 + 1] = s1 + b2[1];
    }
}

// ---------- scatter p[src] -> aggP[dst] (2 floats/edge) ----------
__global__ void scatter_p(const float* __restrict__ p, const int* __restrict__ src,
                          const int* __restrict__ dst, float* __restrict__ aggP) {
    int e = blockIdx.x * blockDim.x + threadIdx.x;
    if (e < N_EDGES) {
        int sd = src[e], dd = dst[e];
        float2 v = *(const float2*)(p + (size_t)sd * 2);
        unsafeAtomicAdd(&aggP[dd * 2 + 0], v.x);
        unsafeAtomicAdd(&aggP[dd * 2 + 1], v.y);
    }
}

// ---------- out = sigmoid(aggP/deg + s) ----------
__global__ void out_kernel(const float* __restrict__ aggP, const float* __restrict__ s,
                           const float* __restrict__ deg, float* __restrict__ out) {
    int i = blockIdx.x * blockDim.x + threadIdx.x;
    if (i < N_NODES * 2) {
        int row = i >> 1;
        float z = aggP[i] / fmaxf(deg[row], 1.0f) + s[i];
        out[i] = 1.0f / (1.0f + expf(-z));
    }
}

extern "C" void kernel_launch(void* const* d_in, const int* in_sizes, int n_in,
                              void* d_out, int out_size, void* d_ws, size_t ws_size,
                              hipStream_t stream) {
    const float* x   = (const float*)d_in[0];
    const int*   ei  = (const int*)d_in[1];
    const float* W1l = (const float*)d_in[2];
    const float* W1r = (const float*)d_in[3];
    const float* b1  = (const float*)d_in[4];
    const float* W2l = (const float*)d_in[5];
    const float* W2r = (const float*)d_in[6];
    const float* b2  = (const float*)d_in[7];

    const int* src = ei;             // edge_index[0]
    const int* dst = ei + N_EDGES;   // edge_index[1]

    float* out = (float*)d_out;                 // [50000, 2]
    float* emb = out + (size_t)N_NODES * 2;     // [50000, 256] == h

    // workspace layout
    float* agg1 = (float*)d_ws;                          // 50000*128
    float* deg  = agg1 + (size_t)N_NODES * D_FEAT;       // 50000
    float* aggP = deg + N_NODES;                         // 100000
    float* p    = aggP + (size_t)N_NODES * 2;            // 100000
    float* s    = p + (size_t)N_NODES * 2;               // 100000

    // zero deg + agg1 + aggP (contiguous block)
    size_t zero_floats = (size_t)N_NODES * D_FEAT + N_NODES + (size_t)N_NODES * 2;
    hipMemsetAsync(agg1, 0, zero_floats * sizeof(float), stream);

    deg_kernel<<<(N_EDGES + 255) / 256, 256, 0, stream>>>(dst, deg);

    scatter_x<<<(N_EDGES * 64) / 256, 256, 0, stream>>>(x, src, dst, agg1);

    gemm1<<<N_NODES / 16, 256, 0, stream>>>(x, agg1, deg, W1l, W1r, b1, emb);

    ps_kernel<<<(N_NODES + 3) / 4, 256, 0, stream>>>(emb, W2l, W2r, b2, p, s);

    scatter_p<<<(N_EDGES + 255) / 256, 256, 0, stream>>>(p, src, dst, aggP);

    out_kernel<<<(N_NODES * 2 + 255) / 256, 256, 0, stream>>>(aggP, s, deg, out);
}

// Round 2
// 437.203 us; speedup vs baseline: 2.5095x; 2.5095x over previous
//
#include <hip/hip_runtime.h>
#include <math.h>

#define N_NODES 50000
#define N_EDGES 800000
#define D_FEAT 128
#define HIDDEN 256
#define NB_SCAN 196  // ceil(50000/256)

// ---------- CSR build: count ----------
__global__ void count_kernel(const int* __restrict__ dst, int* __restrict__ cnt) {
    int e = blockIdx.x * blockDim.x + threadIdx.x;
    if (e < N_EDGES) atomicAdd(&cnt[dst[e]], 1);
}

// ---------- CSR build: block sums ----------
__global__ void scan1(const int* __restrict__ cnt, int* __restrict__ bsum) {
    __shared__ int tmp[256];
    int t = threadIdx.x;
    int i = blockIdx.x * 256 + t;
    tmp[t] = (i < N_NODES) ? cnt[i] : 0;
    __syncthreads();
    for (int off = 128; off > 0; off >>= 1) {
        if (t < off) tmp[t] += tmp[t + off];
        __syncthreads();
    }
    if (t == 0) bsum[blockIdx.x] = tmp[0];
}

// ---------- CSR build: scan of block sums (single block) ----------
__global__ void scan2(const int* __restrict__ bsum, int* __restrict__ boff) {
    __shared__ int tmp[256];
    int t = threadIdx.x;
    int v = (t < NB_SCAN) ? bsum[t] : 0;
    tmp[t] = v;
    __syncthreads();
    for (int off = 1; off < 256; off <<= 1) {
        int y = (t >= off) ? tmp[t - off] : 0;
        __syncthreads();
        tmp[t] += y;
        __syncthreads();
    }
    if (t < NB_SCAN) boff[t] = tmp[t] - v;  // exclusive
}

// ---------- CSR build: per-element exclusive scan -> row begin offsets ----------
__global__ void scan3(const int* __restrict__ cnt, const int* __restrict__ boff,
                      int* __restrict__ rowpos) {
    __shared__ int tmp[256];
    int t = threadIdx.x;
    int i = blockIdx.x * 256 + t;
    int v = (i < N_NODES) ? cnt[i] : 0;
    tmp[t] = v;
    __syncthreads();
    for (int off = 1; off < 256; off <<= 1) {
        int y = (t >= off) ? tmp[t - off] : 0;
        __syncthreads();
        tmp[t] += y;
        __syncthreads();
    }
    if (i < N_NODES) rowpos[i] = tmp[t] - v + boff[blockIdx.x];  // exclusive = beg
}

// ---------- CSR build: scatter edge srcs into dst-sorted order ----------
// after this, rowpos[d] == end offset; beg = rowpos[d] - cnt[d]
__global__ void fill_kernel(const int* __restrict__ src, const int* __restrict__ dst,
                            int* __restrict__ rowpos, unsigned short* __restrict__ esrc) {
    int e = blockIdx.x * blockDim.x + threadIdx.x;
    if (e < N_EDGES) {
        int pos = atomicAdd(&rowpos[dst[e]], 1);
        esrc[pos] = (unsigned short)src[e];  // N_NODES < 65536
    }
}

// ---------- fused layer-1: gather-mean + GEMM: h = relu(mean@W1l + x@W1r + b1) ----------
// block = 256 threads (4 waves), 16 rows per block; each wave gather-means 4 rows.
__global__ __launch_bounds__(256) void gemm1_fused(
    const float* __restrict__ x, const unsigned short* __restrict__ esrc,
    const int* __restrict__ rowend, const int* __restrict__ cnt,
    const float* __restrict__ W1l, const float* __restrict__ W1r,
    const float* __restrict__ b1, float* __restrict__ h) {
    __shared__ float xs[16 * 128];
    __shared__ float ms[16 * 128];

    int r0 = blockIdx.x * 16;
    int tid = threadIdx.x;
    int w = tid >> 6;
    int lane = tid & 63;

    // gather phase: wave w handles rows w*4 .. w*4+3
    for (int rr = 0; rr < 4; rr++) {
        int lr = w * 4 + rr;
        int d = r0 + lr;
        int end = rowend[d];
        int c = cnt[d];
        int beg = end - c;
        float a0 = 0.0f, a1 = 0.0f;
        for (int e = beg; e < end; e++) {
            int s = (int)esrc[e];
            float2 v = *(const float2*)(x + s * 128 + lane * 2);
            a0 += v.x;
            a1 += v.y;
        }
        float inv = 1.0f / fmaxf((float)c, 1.0f);
        ms[lr * 128 + lane * 2 + 0] = a0 * inv;
        ms[lr * 128 + lane * 2 + 1] = a1 * inv;
        float2 xv = *(const float2*)(x + d * 128 + lane * 2);
        xs[lr * 128 + lane * 2 + 0] = xv.x;
        xs[lr * 128 + lane * 2 + 1] = xv.y;
    }
    __syncthreads();

    // GEMM phase: thread owns one output column c = tid
    float acc[16];
#pragma unroll
    for (int r = 0; r < 16; r++) acc[r] = 0.0f;

    int cc = tid;
    for (int k = 0; k < 128; k++) {
        float wl = W1l[k * 256 + cc];
        float wr = W1r[k * 256 + cc];
#pragma unroll
        for (int r = 0; r < 16; r++) {
            acc[r] += ms[r * 128 + k] * wl + xs[r * 128 + k] * wr;
        }
    }
    float b = b1[cc];
#pragma unroll
    for (int r = 0; r < 16; r++) {
        float v = acc[r] + b;
        h[(size_t)(r0 + r) * 256 + cc] = v > 0.0f ? v : 0.0f;
    }
}

// ---------- p = h@W2l, s = h@W2r + b2 (one wave per row) ----------
__global__ void ps_kernel(const float* __restrict__ h, const float* __restrict__ W2l,
                          const float* __restrict__ W2r, const float* __restrict__ b2,
                          float* __restrict__ p, float* __restrict__ s) {
    int row = blockIdx.x * 4 + (threadIdx.x >> 6);
    int lane = threadIdx.x & 63;
    if (row >= N_NODES) return;
    float p0 = 0, p1 = 0, s0 = 0, s1 = 0;
#pragma unroll
    for (int j = 0; j < 4; j++) {
        int cc = lane + j * 64;
        float hv = h[(size_t)row * 256 + cc];
        p0 += hv * W2l[cc * 2 + 0];
        p1 += hv * W2l[cc * 2 + 1];
        s0 += hv * W2r[cc * 2 + 0];
        s1 += hv * W2r[cc * 2 + 1];
    }
#pragma unroll
    for (int off = 32; off > 0; off >>= 1) {
        p0 += __shfl_down(p0, off);
        p1 += __shfl_down(p1, off);
        s0 += __shfl_down(s0, off);
        s1 += __shfl_down(s1, off);
    }
    if (lane == 0) {
        p[row * 2 + 0] = p0;
        p[row * 2 + 1] = p1;
        s[row * 2 + 0] = s0 + b2[0];
        s[row * 2 + 1] = s1 + b2[1];
    }
}

// ---------- layer-2 gather-mean + sigmoid ----------
__global__ void aggregate2(const float* __restrict__ p, const float* __restrict__ s,
                           const unsigned short* __restrict__ esrc,
                           const int* __restrict__ rowend, const int* __restrict__ cnt,
                           float* __restrict__ out) {
    int d = blockIdx.x * blockDim.x + threadIdx.x;
    if (d >= N_NODES) return;
    int end = rowend[d];
    int c = cnt[d];
    int beg = end - c;
    float a0 = 0.0f, a1 = 0.0f;
    for (int e = beg; e < end; e++) {
        int ss = (int)esrc[e];
        a0 += p[ss * 2 + 0];
        a1 += p[ss * 2 + 1];
    }
    float inv = 1.0f / fmaxf((float)c, 1.0f);
    float z0 = a0 * inv + s[d * 2 + 0];
    float z1 = a1 * inv + s[d * 2 + 1];
    out[d * 2 + 0] = 1.0f / (1.0f + expf(-z0));
    out[d * 2 + 1] = 1.0f / (1.0f + expf(-z1));
}

extern "C" void kernel_launch(void* const* d_in, const int* in_sizes, int n_in,
                              void* d_out, int out_size, void* d_ws, size_t ws_size,
                              hipStream_t stream) {
    const float* x   = (const float*)d_in[0];
    const int*   ei  = (const int*)d_in[1];
    const float* W1l = (const float*)d_in[2];
    const float* W1r = (const float*)d_in[3];
    const float* b1  = (const float*)d_in[4];
    const float* W2l = (const float*)d_in[5];
    const float* W2r = (const float*)d_in[6];
    const float* b2  = (const float*)d_in[7];

    const int* src = ei;             // edge_index[0]
    const int* dst = ei + N_EDGES;   // edge_index[1]

    float* out = (float*)d_out;                 // [50000, 2]
    float* emb = out + (size_t)N_NODES * 2;     // [50000, 256] == h

    // workspace layout (ints/floats, ~2.8 MB total)
    int* cnt    = (int*)d_ws;                    // 50000
    int* rowpos = cnt + N_NODES;                 // 50000 (beg, then end after fill)
    int* bsum   = rowpos + N_NODES;              // 256
    int* boff   = bsum + 256;                    // 256
    unsigned short* esrc = (unsigned short*)(boff + 256);  // 800000 ushort
    float* p    = (float*)(esrc + N_EDGES);      // 100000
    float* s    = p + (size_t)N_NODES * 2;       // 100000

    hipMemsetAsync(cnt, 0, N_NODES * sizeof(int), stream);

    count_kernel<<<(N_EDGES + 255) / 256, 256, 0, stream>>>(dst, cnt);
    scan1<<<NB_SCAN, 256, 0, stream>>>(cnt, bsum);
    scan2<<<1, 256, 0, stream>>>(bsum, boff);
    scan3<<<NB_SCAN, 256, 0, stream>>>(cnt, boff, rowpos);
    fill_kernel<<<(N_EDGES + 255) / 256, 256, 0, stream>>>(src, dst, rowpos, esrc);

    gemm1_fused<<<N_NODES / 16, 256, 0, stream>>>(x, esrc, rowpos, cnt, W1l, W1r, b1, emb);

    ps_kernel<<<(N_NODES + 3) / 4, 256, 0, stream>>>(emb, W2l, W2r, b2, p, s);

    aggregate2<<<(N_NODES + 255) / 256, 256, 0, stream>>>(p, s, esrc, rowpos, cnt, out);
}

// Round 3
// 333.443 us; speedup vs baseline: 3.2904x; 1.3112x over previous
//
#include <hip/hip_runtime.h>
#include <math.h>

#define N_NODES 50000
#define N_EDGES 800000
#define D_FEAT 128
#define HIDDEN 256
#define NB_SCAN 196  // ceil(50000/256)

typedef __bf16 bf16x8 __attribute__((ext_vector_type(8)));
typedef float f32x4 __attribute__((ext_vector_type(4)));

__device__ __forceinline__ unsigned short f2b(float f) {
    unsigned u = __builtin_bit_cast(unsigned, f);
    return (unsigned short)((u + 0x7fff + ((u >> 16) & 1)) >> 16);  // RNE
}

// ---------- x (fp32) -> packed bf16 pairs ----------
__global__ void cvt_x(const float* __restrict__ x, unsigned* __restrict__ xb2) {
    int t = blockIdx.x * blockDim.x + threadIdx.x;  // 3.2M
    if (t < N_NODES * 64) {
        float2 v = *(const float2*)(x + (size_t)t * 2);
        xb2[t] = (unsigned)f2b(v.x) | ((unsigned)f2b(v.y) << 16);
    }
}

// ---------- W1l/W1r -> MFMA B-fragment-swizzled bf16 ----------
// Wcat[k][n]: k<128 -> W1l[k][n], else W1r[k-128][n].  K=256, N=256.
// Wfrag linear index t = ((nt*8 + ks)*64 + lane)*8 + j
//   holds Wcat[ks*32 + (lane>>4)*8 + j][nt*16 + (lane&15)]
__global__ void build_wfrag(const float* __restrict__ W1l, const float* __restrict__ W1r,
                            unsigned short* __restrict__ Wfrag) {
    int t = blockIdx.x * 256 + threadIdx.x;  // 0..65535
    int j = t & 7;
    int lane = (t >> 3) & 63;
    int ks = (t >> 9) & 7;
    int nt = t >> 12;
    int k = ks * 32 + ((lane >> 4) << 3) + j;
    int n = (nt << 4) + (lane & 15);
    float v = (k < 128) ? W1l[k * 256 + n] : W1r[(k - 128) * 256 + n];
    Wfrag[t] = f2b(v);
}

// ---------- CSR build ----------
__global__ void count_kernel(const int* __restrict__ dst, int* __restrict__ cnt) {
    int e = blockIdx.x * blockDim.x + threadIdx.x;
    if (e < N_EDGES) atomicAdd(&cnt[dst[e]], 1);
}

__global__ void scan1(const int* __restrict__ cnt, int* __restrict__ bsum) {
    __shared__ int tmp[256];
    int t = threadIdx.x;
    int i = blockIdx.x * 256 + t;
    tmp[t] = (i < N_NODES) ? cnt[i] : 0;
    __syncthreads();
    for (int off = 128; off > 0; off >>= 1) {
        if (t < off) tmp[t] += tmp[t + off];
        __syncthreads();
    }
    if (t == 0) bsum[blockIdx.x] = tmp[0];
}

__global__ void scan2(const int* __restrict__ bsum, int* __restrict__ boff) {
    __shared__ int tmp[256];
    int t = threadIdx.x;
    int v = (t < NB_SCAN) ? bsum[t] : 0;
    tmp[t] = v;
    __syncthreads();
    for (int off = 1; off < 256; off <<= 1) {
        int y = (t >= off) ? tmp[t - off] : 0;
        __syncthreads();
        tmp[t] += y;
        __syncthreads();
    }
    if (t < NB_SCAN) boff[t] = tmp[t] - v;
}

__global__ void scan3(const int* __restrict__ cnt, const int* __restrict__ boff,
                      int* __restrict__ rowpos) {
    __shared__ int tmp[256];
    int t = threadIdx.x;
    int i = blockIdx.x * 256 + t;
    int v = (i < N_NODES) ? cnt[i] : 0;
    tmp[t] = v;
    __syncthreads();
    for (int off = 1; off < 256; off <<= 1) {
        int y = (t >= off) ? tmp[t - off] : 0;
        __syncthreads();
        tmp[t] += y;
        __syncthreads();
    }
    if (i < N_NODES) rowpos[i] = tmp[t] - v + boff[blockIdx.x];
}

// after fill, rowpos[d] == end offset; beg = end - cnt[d]
__global__ void fill_kernel(const int* __restrict__ src, const int* __restrict__ dst,
                            int* __restrict__ rowpos, unsigned short* __restrict__ esrc) {
    int e = blockIdx.x * blockDim.x + threadIdx.x;
    if (e < N_EDGES) {
        int pos = atomicAdd(&rowpos[dst[e]], 1);
        esrc[pos] = (unsigned short)src[e];
    }
}

// ---------- fused layer-1: bf16 gather-mean + MFMA GEMM ----------
// 64 rows per block, 256 threads (4 waves). h = relu([mean|x] @ Wcat + b1)
__global__ __launch_bounds__(256) void gemm1_mfma(
    const unsigned* __restrict__ xb2, const unsigned short* __restrict__ esrc,
    const int* __restrict__ rowend, const int* __restrict__ cnt,
    const unsigned short* __restrict__ Wfrag, const float* __restrict__ b1,
    float* __restrict__ h) {
    // A tile: 64 rows x 256 bf16 (k: 0-127 mean, 128-255 x), padded to 132 uints/row
    __shared__ unsigned A[64][132];

    int r0 = blockIdx.x * 64;
    int tid = threadIdx.x;
    int w = tid >> 6;
    int lane = tid & 63;

    // ---- gather phase: wave w handles rows w*16 .. w*16+15 ----
    for (int rr = 0; rr < 16; rr++) {
        int lr = (w << 4) + rr;
        int d = r0 + lr;
        if (d < N_NODES) {
            int end = rowend[d];
            int c = cnt[d];
            float a0 = 0.0f, a1 = 0.0f;
            for (int ch = end - c; ch < end; ch += 64) {
                int idx = ch + lane;
                int e = (idx < end) ? (int)esrc[idx] : 0;  // coalesced index load
                int m = end - ch;
                if (m > 64) m = 64;
#pragma unroll 4
                for (int j = 0; j < m; j++) {
                    int s = __shfl(e, j);                   // broadcast, no mem op
                    unsigned u = xb2[s * 64 + lane];        // 2 bf16 features
                    a0 += __builtin_bit_cast(float, u << 16);
                    a1 += __builtin_bit_cast(float, u & 0xffff0000u);
                }
            }
            float inv = 1.0f / fmaxf((float)c, 1.0f);
            unsigned lo = (unsigned)f2b(a0 * inv);
            unsigned hi = (unsigned)f2b(a1 * inv);
            A[lr][lane] = lo | (hi << 16);
            A[lr][64 + lane] = xb2[d * 64 + lane];
        } else {
            A[lr][lane] = 0;
            A[lr][64 + lane] = 0;
        }
    }
    __syncthreads();

    // ---- MFMA phase: wave w computes cols w*64..w*64+63 for all 64 rows ----
    f32x4 acc[16];  // [mt][nt]
#pragma unroll
    for (int i = 0; i < 16; i++) acc[i] = (f32x4){0.0f, 0.0f, 0.0f, 0.0f};

    int quad = lane >> 4;
    int l15 = lane & 15;

    for (int ks = 0; ks < 8; ks++) {
        bf16x8 bfr[4];
#pragma unroll
        for (int nt = 0; nt < 4; nt++) {
            int ntg = (w << 2) + nt;
            uint4 raw = *(const uint4*)(Wfrag + ((((ntg << 3) + ks) << 6) + lane) * 8);
            bfr[nt] = __builtin_bit_cast(bf16x8, raw);
        }
#pragma unroll
        for (int mt = 0; mt < 4; mt++) {
            int row = (mt << 4) + l15;
            uint4 araw = *(const uint4*)((const char*)&A[row][0] + ks * 64 + quad * 16);
            bf16x8 afr = __builtin_bit_cast(bf16x8, araw);
#pragma unroll
            for (int nt = 0; nt < 4; nt++) {
                acc[(mt << 2) + nt] = __builtin_amdgcn_mfma_f32_16x16x32_bf16(
                    afr, bfr[nt], acc[(mt << 2) + nt], 0, 0, 0);
            }
        }
    }

    // ---- epilogue: relu + store. D layout: col=lane&15, row=quad*4+reg ----
    int colbase = w << 6;
#pragma unroll
    for (int mt = 0; mt < 4; mt++) {
        int rowb = r0 + (mt << 4) + (quad << 2);
#pragma unroll
        for (int nt = 0; nt < 4; nt++) {
            int col = colbase + (nt << 4) + l15;
            float b = b1[col];
            f32x4 v = acc[(mt << 2) + nt];
#pragma unroll
            for (int r = 0; r < 4; r++) {
                int row = rowb + r;
                if (row < N_NODES) {
                    float vv = v[r] + b;
                    h[(size_t)row * 256 + col] = vv > 0.0f ? vv : 0.0f;
                }
            }
        }
    }
}

// ---------- p = h@W2l, s = h@W2r + b2 (one wave per row) ----------
__global__ void ps_kernel(const float* __restrict__ h, const float* __restrict__ W2l,
                          const float* __restrict__ W2r, const float* __restrict__ b2,
                          float* __restrict__ p, float* __restrict__ s) {
    int row = blockIdx.x * 4 + (threadIdx.x >> 6);
    int lane = threadIdx.x & 63;
    if (row >= N_NODES) return;
    float p0 = 0, p1 = 0, s0 = 0, s1 = 0;
#pragma unroll
    for (int j = 0; j < 4; j++) {
        int cc = lane + j * 64;
        float hv = h[(size_t)row * 256 + cc];
        p0 += hv * W2l[cc * 2 + 0];
        p1 += hv * W2l[cc * 2 + 1];
        s0 += hv * W2r[cc * 2 + 0];
        s1 += hv * W2r[cc * 2 + 1];
    }
#pragma unroll
    for (int off = 32; off > 0; off >>= 1) {
        p0 += __shfl_down(p0, off);
        p1 += __shfl_down(p1, off);
        s0 += __shfl_down(s0, off);
        s1 += __shfl_down(s1, off);
    }
    if (lane == 0) {
        p[row * 2 + 0] = p0;
        p[row * 2 + 1] = p1;
        s[row * 2 + 0] = s0 + b2[0];
        s[row * 2 + 1] = s1 + b2[1];
    }
}

// ---------- layer-2 gather-mean + sigmoid ----------
__global__ void aggregate2(const float* __restrict__ p, const float* __restrict__ s,
                           const unsigned short* __restrict__ esrc,
                           const int* __restrict__ rowend, const int* __restrict__ cnt,
                           float* __restrict__ out) {
    int d = blockIdx.x * blockDim.x + threadIdx.x;
    if (d >= N_NODES) return;
    int end = rowend[d];
    int c = cnt[d];
    float a0 = 0.0f, a1 = 0.0f;
    for (int e = end - c; e < end; e++) {
        int ss = (int)esrc[e];
        a0 += p[ss * 2 + 0];
        a1 += p[ss * 2 + 1];
    }
    float inv = 1.0f / fmaxf((float)c, 1.0f);
    float z0 = a0 * inv + s[d * 2 + 0];
    float z1 = a1 * inv + s[d * 2 + 1];
    out[d * 2 + 0] = 1.0f / (1.0f + expf(-z0));
    out[d * 2 + 1] = 1.0f / (1.0f + expf(-z1));
}

extern "C" void kernel_launch(void* const* d_in, const int* in_sizes, int n_in,
                              void* d_out, int out_size, void* d_ws, size_t ws_size,
                              hipStream_t stream) {
    const float* x   = (const float*)d_in[0];
    const int*   ei  = (const int*)d_in[1];
    const float* W1l = (const float*)d_in[2];
    const float* W1r = (const float*)d_in[3];
    const float* b1  = (const float*)d_in[4];
    const float* W2l = (const float*)d_in[5];
    const float* W2r = (const float*)d_in[6];
    const float* b2  = (const float*)d_in[7];

    const int* src = ei;
    const int* dst = ei + N_EDGES;

    float* out = (float*)d_out;               // [50000, 2]
    float* emb = out + (size_t)N_NODES * 2;   // [50000, 256] == h

    // workspace layout (~16 MB)
    int* cnt    = (int*)d_ws;                             // 50000
    int* rowpos = cnt + N_NODES;                          // 50000
    int* bsum   = rowpos + N_NODES;                       // 256
    int* boff   = bsum + 256;                             // 256
    unsigned short* esrc = (unsigned short*)(boff + 256); // 800000 ushort
    unsigned* xb2 = (unsigned*)(esrc + N_EDGES);          // 3.2M uint (12.8 MB)
    unsigned short* Wfrag = (unsigned short*)(xb2 + (size_t)N_NODES * 64);  // 65536
    float* p = (float*)(Wfrag + 65536);                   // 100000
    float* s = p + (size_t)N_NODES * 2;                   // 100000

    hipMemsetAsync(cnt, 0, N_NODES * sizeof(int), stream);

    cvt_x<<<(N_NODES * 64 + 255) / 256, 256, 0, stream>>>(x, xb2);
    build_wfrag<<<256, 256, 0, stream>>>(W1l, W1r, Wfrag);

    count_kernel<<<(N_EDGES + 255) / 256, 256, 0, stream>>>(dst, cnt);
    scan1<<<NB_SCAN, 256, 0, stream>>>(cnt, bsum);
    scan2<<<1, 256, 0, stream>>>(bsum, boff);
    scan3<<<NB_SCAN, 256, 0, stream>>>(cnt, boff, rowpos);
    fill_kernel<<<(N_EDGES + 255) / 256, 256, 0, stream>>>(src, dst, rowpos, esrc);

    gemm1_mfma<<<(N_NODES + 63) / 64, 256, 0, stream>>>(xb2, esrc, rowpos, cnt,
                                                        Wfrag, b1, emb);

    ps_kernel<<<(N_NODES + 3) / 4, 256, 0, stream>>>(emb, W2l, W2r, b2, p, s);

    aggregate2<<<(N_NODES + 255) / 256, 256, 0, stream>>>(p, s, esrc, rowpos, cnt, out);
}

// Round 4
// 258.369 us; speedup vs baseline: 4.2465x; 1.2906x over previous
//
#include <hip/hip_runtime.h>
#include <math.h>

#define N_NODES 50000
#define N_EDGES 800000
#define D_FEAT 128
#define HIDDEN 256
#define NB_SCAN 196           // ceil(50000/256)
#define NB_CVT 12500          // 3.2M threads / 256
#define NB_CNT 3125           // 800000 / 256
#define NB_WF 256             // 65536 / 256
#define GEMM_BLOCKS 782       // ceil(50000/64)

typedef __bf16 bf16x8 __attribute__((ext_vector_type(8)));
typedef float f32x4 __attribute__((ext_vector_type(4)));

__device__ __forceinline__ unsigned short f2b(float f) {
    unsigned u = __builtin_bit_cast(unsigned, f);
    return (unsigned short)((u + 0x7fff + ((u >> 16) & 1)) >> 16);  // RNE
}

// ---------- fused prep: cvt_x | count | build_wfrag (block-range dispatch) ----------
// Arow[node][128 uints]: uints 0..63 = mean (bf16x2, filled by agg1), 64..127 = x (bf16x2)
__global__ __launch_bounds__(256) void prep(
    const float* __restrict__ x, const int* __restrict__ dst,
    const float* __restrict__ W1l, const float* __restrict__ W1r,
    unsigned* __restrict__ Arow, int* __restrict__ cnt,
    unsigned short* __restrict__ Wfrag) {
    int b = blockIdx.x;
    if (b < NB_CVT) {
        int t = b * 256 + threadIdx.x;          // 0..3.2M-1
        float2 v = *(const float2*)(x + (size_t)t * 2);
        int d = t >> 6, j = t & 63;
        Arow[(size_t)d * 128 + 64 + j] = (unsigned)f2b(v.x) | ((unsigned)f2b(v.y) << 16);
    } else if (b < NB_CVT + NB_CNT) {
        int e = (b - NB_CVT) * 256 + threadIdx.x;  // 0..799999
        atomicAdd(&cnt[dst[e]], 1);
    } else {
        int t = (b - NB_CVT - NB_CNT) * 256 + threadIdx.x;  // 0..65535
        int j = t & 7;
        int lane = (t >> 3) & 63;
        int ks = (t >> 9) & 7;
        int nt = t >> 12;
        int k = ks * 32 + ((lane >> 4) << 3) + j;
        int n = (nt << 4) + (lane & 15);
        float v = (k < 128) ? W1l[k * 256 + n] : W1r[(k - 128) * 256 + n];
        Wfrag[t] = f2b(v);
    }
}

// ---------- CSR build: scans ----------
__global__ void scan1(const int* __restrict__ cnt, int* __restrict__ bsum) {
    __shared__ int tmp[256];
    int t = threadIdx.x;
    int i = blockIdx.x * 256 + t;
    tmp[t] = (i < N_NODES) ? cnt[i] : 0;
    __syncthreads();
    for (int off = 128; off > 0; off >>= 1) {
        if (t < off) tmp[t] += tmp[t + off];
        __syncthreads();
    }
    if (t == 0) bsum[blockIdx.x] = tmp[0];
}

__global__ void scan2(const int* __restrict__ bsum, int* __restrict__ boff) {
    __shared__ int tmp[256];
    int t = threadIdx.x;
    int v = (t < NB_SCAN) ? bsum[t] : 0;
    tmp[t] = v;
    __syncthreads();
    for (int off = 1; off < 256; off <<= 1) {
        int y = (t >= off) ? tmp[t - off] : 0;
        __syncthreads();
        tmp[t] += y;
        __syncthreads();
    }
    if (t < NB_SCAN) boff[t] = tmp[t] - v;
}

__global__ void scan3(const int* __restrict__ cnt, const int* __restrict__ boff,
                      int* __restrict__ rowpos) {
    __shared__ int tmp[256];
    int t = threadIdx.x;
    int i = blockIdx.x * 256 + t;
    int v = (i < N_NODES) ? cnt[i] : 0;
    tmp[t] = v;
    __syncthreads();
    for (int off = 1; off < 256; off <<= 1) {
        int y = (t >= off) ? tmp[t - off] : 0;
        __syncthreads();
        tmp[t] += y;
        __syncthreads();
    }
    if (i < N_NODES) rowpos[i] = tmp[t] - v + boff[blockIdx.x];
}

// after fill, rowpos[d] == end offset; beg = end - cnt[d]
__global__ void fill_kernel(const int* __restrict__ src, const int* __restrict__ dst,
                            int* __restrict__ rowpos, unsigned short* __restrict__ esrc) {
    int e = blockIdx.x * blockDim.x + threadIdx.x;
    if (e < N_EDGES) {
        int pos = atomicAdd(&rowpos[dst[e]], 1);
        esrc[pos] = (unsigned short)src[e];
    }
}

// ---------- agg1: one WAVE per node, gather-mean of x (bf16) -> Arow mean half ----------
__global__ __launch_bounds__(256) void agg1(
    const unsigned* __restrict__ Arow_x, unsigned* __restrict__ Arow_m,
    const unsigned short* __restrict__ esrc,
    const int* __restrict__ rowend, const int* __restrict__ cnt) {
    int d = blockIdx.x * 4 + (threadIdx.x >> 6);   // grid covers exactly 50000
    int lane = threadIdx.x & 63;
    int end = rowend[d];
    int c = cnt[d];
    float a0 = 0.0f, a1 = 0.0f;
    for (int base = end - c; base < end; base += 64) {
        int m = end - base; if (m > 64) m = 64;
        int idx = base + lane;
        int e = (int)esrc[idx < end ? idx : end - 1];  // coalesced, clamped
        for (int j0 = 0; j0 < m; j0 += 8) {
#pragma unroll
            for (int j = 0; j < 8; j++) {
                int s = __shfl(e, j0 + j);                        // broadcast
                unsigned u = Arow_x[(size_t)s * 128 + 64 + lane]; // x half, 2 bf16
                float sc = (j0 + j < m) ? 1.0f : 0.0f;            // uniform mask
                a0 += sc * __builtin_bit_cast(float, u << 16);
                a1 += sc * __builtin_bit_cast(float, u & 0xffff0000u);
            }
        }
    }
    float inv = 1.0f / fmaxf((float)c, 1.0f);
    unsigned lo = (unsigned)f2b(a0 * inv);
    unsigned hi = (unsigned)f2b(a1 * inv);
    Arow_m[(size_t)d * 128 + lane] = lo | (hi << 16);
}

// ---------- gemm1 + fused ps: h = relu([mean|x]@Wcat + b1); p = h@W2l; s = h@W2r + b2 ----------
// 64 rows/block, 256 thr (4 waves); wave w owns cols w*64..w*64+63.
__global__ __launch_bounds__(256) void gemm1ps(
    const unsigned* __restrict__ Arow, const unsigned short* __restrict__ Wfrag,
    const float* __restrict__ b1, const float* __restrict__ W2l,
    const float* __restrict__ W2r, const float* __restrict__ b2,
    float* __restrict__ h, float* __restrict__ p, float* __restrict__ s) {
    __shared__ unsigned A[64 * 128];   // 32 KB, 16B-chunk XOR swizzled
    __shared__ float ppart[64][4];     // p0,p1,s0,s1 partials per row

    int r0 = blockIdx.x * 64;
    int tid = threadIdx.x;
    int w = tid >> 6;
    int lane = tid & 63;
    int quad = lane >> 4;
    int l15 = lane & 15;

    ((float*)ppart)[tid] = 0.0f;       // 256 floats exactly

    // ---- stage A tile (swizzled): thread t -> row t>>2, chunks (t&3)*8+j ----
    int sr = tid >> 2;
    int cb = (tid & 3) << 3;
#pragma unroll
    for (int j = 0; j < 8; j++) {
        int c = cb + j;
        uint4 v = *(const uint4*)(Arow + (size_t)(r0 + sr) * 128 + (c << 2));
        int cp = c ^ (sr & 7);
        *(uint4*)(A + sr * 128 + (cp << 2)) = v;
    }
    __syncthreads();

    // ---- MFMA: 8 K-chunks of 32 ----
    f32x4 acc[16];
#pragma unroll
    for (int i = 0; i < 16; i++) acc[i] = (f32x4){0.0f, 0.0f, 0.0f, 0.0f};

    for (int ks = 0; ks < 8; ks++) {
        bf16x8 bfr[4];
#pragma unroll
        for (int nt = 0; nt < 4; nt++) {
            int ntg = (w << 2) + nt;
            uint4 raw = *(const uint4*)(Wfrag + ((((ntg << 3) + ks) << 6) + lane) * 8);
            bfr[nt] = __builtin_bit_cast(bf16x8, raw);
        }
#pragma unroll
        for (int mt = 0; mt < 4; mt++) {
            int row = (mt << 4) + l15;
            int c = (ks << 2) + quad;
            uint4 araw = *(const uint4*)(A + row * 128 + ((c ^ (row & 7)) << 2));
            bf16x8 afr = __builtin_bit_cast(bf16x8, araw);
#pragma unroll
            for (int nt = 0; nt < 4; nt++) {
                acc[(mt << 2) + nt] = __builtin_amdgcn_mfma_f32_16x16x32_bf16(
                    afr, bfr[nt], acc[(mt << 2) + nt], 0, 0, 0);
            }
        }
    }

    // ---- epilogue: relu + h store + ps partials ----
    float w2[4][4];
#pragma unroll
    for (int nt = 0; nt < 4; nt++) {
        int col = (w << 6) + (nt << 4) + l15;
        float2 l2 = *(const float2*)(W2l + col * 2);
        float2 r2 = *(const float2*)(W2r + col * 2);
        w2[nt][0] = l2.x; w2[nt][1] = l2.y; w2[nt][2] = r2.x; w2[nt][3] = r2.y;
    }

#pragma unroll
    for (int mt = 0; mt < 4; mt++) {
        float red[4][4];
#pragma unroll
        for (int v = 0; v < 4; v++)
#pragma unroll
            for (int r = 0; r < 4; r++) red[v][r] = 0.0f;

#pragma unroll
        for (int nt = 0; nt < 4; nt++) {
            int col = (w << 6) + (nt << 4) + l15;
            float b = b1[col];
            f32x4 v = acc[(mt << 2) + nt];
#pragma unroll
            for (int r = 0; r < 4; r++) {
                float hv = v[r] + b;
                hv = hv > 0.0f ? hv : 0.0f;
                int row = r0 + (mt << 4) + (quad << 2) + r;
                if (row < N_NODES) h[(size_t)row * 256 + col] = hv;
                red[0][r] += hv * w2[nt][0];
                red[1][r] += hv * w2[nt][1];
                red[2][r] += hv * w2[nt][2];
                red[3][r] += hv * w2[nt][3];
            }
        }
        // reduce across the 16 l15 lanes (stays within quad)
#pragma unroll
        for (int v = 0; v < 4; v++)
#pragma unroll
            for (int r = 0; r < 4; r++) {
                red[v][r] += __shfl_xor(red[v][r], 1);
                red[v][r] += __shfl_xor(red[v][r], 2);
                red[v][r] += __shfl_xor(red[v][r], 4);
                red[v][r] += __shfl_xor(red[v][r], 8);
            }
        if (l15 == 0) {
            int lrow = (mt << 4) + (quad << 2);
#pragma unroll
            for (int r = 0; r < 4; r++)
#pragma unroll
                for (int v = 0; v < 4; v++)
                    atomicAdd(&ppart[lrow + r][v], red[v][r]);
        }
    }
    __syncthreads();

    if (tid < 64) {
        int row = r0 + tid;
        if (row < N_NODES) {
            float2 pv = {ppart[tid][0], ppart[tid][1]};
            float2 sv = {ppart[tid][2] + b2[0], ppart[tid][3] + b2[1]};
            *(float2*)(p + (size_t)row * 2) = pv;
            *(float2*)(s + (size_t)row * 2) = sv;
        }
    }
}

// ---------- layer-2: one WAVE per node, gather-mean of p + sigmoid ----------
__global__ __launch_bounds__(256) void agg2(
    const float* __restrict__ p, const float* __restrict__ s,
    const unsigned short* __restrict__ esrc,
    const int* __restrict__ rowend, const int* __restrict__ cnt,
    float* __restrict__ out) {
    int d = blockIdx.x * 4 + (threadIdx.x >> 6);   // exactly 50000
    int lane = threadIdx.x & 63;
    int end = rowend[d];
    int c = cnt[d];
    float a0 = 0.0f, a1 = 0.0f;
    for (int base = end - c; base < end; base += 64) {
        int idx = base + lane;
        if (idx < end) {
            int ss = (int)esrc[idx];
            float2 v = *(const float2*)(p + (size_t)ss * 2);
            a0 += v.x; a1 += v.y;
        }
    }
#pragma unroll
    for (int off = 32; off > 0; off >>= 1) {
        a0 += __shfl_down(a0, off);
        a1 += __shfl_down(a1, off);
    }
    if (lane == 0) {
        float inv = 1.0f / fmaxf((float)c, 1.0f);
        float z0 = a0 * inv + s[(size_t)d * 2 + 0];
        float z1 = a1 * inv + s[(size_t)d * 2 + 1];
        float2 o = {1.0f / (1.0f + expf(-z0)), 1.0f / (1.0f + expf(-z1))};
        *(float2*)(out + (size_t)d * 2) = o;
    }
}

extern "C" void kernel_launch(void* const* d_in, const int* in_sizes, int n_in,
                              void* d_out, int out_size, void* d_ws, size_t ws_size,
                              hipStream_t stream) {
    const float* x   = (const float*)d_in[0];
    const int*   ei  = (const int*)d_in[1];
    const float* W1l = (const float*)d_in[2];
    const float* W1r = (const float*)d_in[3];
    const float* b1  = (const float*)d_in[4];
    const float* W2l = (const float*)d_in[5];
    const float* W2r = (const float*)d_in[6];
    const float* b2  = (const float*)d_in[7];

    const int* src = ei;
    const int* dst = ei + N_EDGES;

    float* out = (float*)d_out;               // [50000, 2]
    float* emb = out + (size_t)N_NODES * 2;   // [50000, 256] == h

    // ---- workspace layout (~28.6 MB) ----
    int* cnt    = (int*)d_ws;                             // 50000
    int* rowpos = cnt + N_NODES;                          // 50000
    int* bsum   = rowpos + N_NODES;                       // 256
    int* boff   = bsum + 256;                             // 256
    unsigned short* esrc = (unsigned short*)(boff + 256); // 800064 (pad, 16B-mult)
    unsigned* Arow = (unsigned*)(esrc + 800064);          // 50048 rows x 128 uints
    unsigned short* Wfrag = (unsigned short*)(Arow + (size_t)50048 * 128);  // 65536
    float* p = (float*)(Wfrag + 65536);                   // 100000
    float* s = p + (size_t)N_NODES * 2;                   // 100000

    hipMemsetAsync(cnt, 0, N_NODES * sizeof(int), stream);

    prep<<<NB_CVT + NB_CNT + NB_WF, 256, 0, stream>>>(x, dst, W1l, W1r, Arow, cnt, Wfrag);

    scan1<<<NB_SCAN, 256, 0, stream>>>(cnt, bsum);
    scan2<<<1, 256, 0, stream>>>(bsum, boff);
    scan3<<<NB_SCAN, 256, 0, stream>>>(cnt, boff, rowpos);
    fill_kernel<<<NB_CNT, 256, 0, stream>>>(src, dst, rowpos, esrc);

    agg1<<<N_NODES / 4, 256, 0, stream>>>(Arow, Arow, esrc, rowpos, cnt);

    gemm1ps<<<GEMM_BLOCKS, 256, 0, stream>>>(Arow, Wfrag, b1, W2l, W2r, b2, emb, p, s);

    agg2<<<N_NODES / 4, 256, 0, stream>>>(p, s, esrc, rowpos, cnt, out);
}